// Round 2
// baseline (928.183 us; speedup 1.0000x reference)
//
#include <hip/hip_runtime.h>
#include <math.h>

// ---------------------------------------------------------------------------
// QINRLayer: Linear+BN -> 10-qubit QNN (statevector sim) -> classical branch
// One wave per sample; 1024 complex amps in registers (16/lane).
// k = lane*16 + j ; wire w (0=MSB) <-> lane bit (5-w) for w<6, j bit (9-w) else.
//
// Circuit algebra used (all exact):
//   U0|0..0> is a product state -> direct init, no gate pass.
//   encode(E) then param layer U_{k+1} fuse into F_k = U_{k+1} * E.
//   CNOTs (0,1)..(4,5) compose into lane perm  src = lane ^ (lane>>1).
//   rz3 is diagonal -> outs[3] == outs[2]; 4th measure dropped.
// ---------------------------------------------------------------------------

#define R0 0.70710678118654752f

// ws layout (floats)
#define WS_XQ    0         // 8192*40
#define WS_X1    327680    // 8192*40   (ps1/ps2 alias this region, consumed first)
#define WS_PS1   327680    // 40*1024
#define WS_PS2   368640    // 40*1024
#define WS_BNA   655360    // 40
#define WS_BNC   655400    // 40
#define WS_GATES 655440    // 40 gates * 8 floats (fused rz2*ry1*rz1 per block,wire)

// ---------------- gate primitives (state in registers) ---------------------

template<int M>
__device__ __forceinline__ void gen_local(float (&sr)[16], float (&si)[16],
    float g00r,float g00i,float g01r,float g01i,
    float g10r,float g10i,float g11r,float g11i)
{
#pragma unroll
  for (int j=0;j<16;++j) if (!(j&M)) {
    const int j1=j|M;
    float ar=sr[j],ai=si[j],br=sr[j1],bi=si[j1];
    sr[j]  = g00r*ar - g00i*ai + g01r*br - g01i*bi;
    si[j]  = g00r*ai + g00i*ar + g01r*bi + g01i*br;
    sr[j1] = g10r*ar - g10i*ai + g11r*br - g11i*bi;
    si[j1] = g10r*ai + g10i*ar + g11r*bi + g11i*br;
  }
}

template<int LM>
__device__ __forceinline__ void gen_cross(float (&sr)[16], float (&si)[16], int lane,
    float g00r,float g00i,float g01r,float g01i,
    float g10r,float g10i,float g11r,float g11i)
{
  const bool hi = (lane & LM) != 0;
  const float gar = hi ? g11r : g00r;
  const float gai = hi ? g11i : g00i;
  const float gbr = hi ? g10r : g01r;
  const float gbi = hi ? g10i : g01i;
#pragma unroll
  for (int j=0;j<16;++j) {
    float pr = __shfl_xor(sr[j], LM, 64);
    float pi = __shfl_xor(si[j], LM, 64);
    float mr = sr[j], mi = si[j];
    sr[j] = gar*mr - gai*mi + gbr*pr - gbi*pi;
    si[j] = gar*mi + gai*mr + gbr*pi + gbi*pr;
  }
}

template<int W>
__device__ __forceinline__ void gen_wire(float (&sr)[16], float (&si)[16], int lane,
                                         const float* g)
{
  float g00r=g[0],g00i=g[1],g01r=g[2],g01i=g[3],g10r=g[4],g10i=g[5],g11r=g[6],g11i=g[7];
  if constexpr (W < 6) gen_cross<(1<<(5-W))>(sr,si,lane,g00r,g00i,g01r,g01i,g10r,g10i,g11r,g11i);
  else                 gen_local<(1<<(9-W))>(sr,si,g00r,g00i,g01r,g01i,g10r,g10i,g11r,g11i);
}

// Hadamard
template<int M>
__device__ __forceinline__ void h_local(float (&sr)[16], float (&si)[16])
{
#pragma unroll
  for (int j=0;j<16;++j) if (!(j&M)) {
    const int j1=j|M;
    float ar=sr[j],ai=si[j],br=sr[j1],bi=si[j1];
    sr[j]=R0*(ar+br);  si[j]=R0*(ai+bi);
    sr[j1]=R0*(ar-br); si[j1]=R0*(ai-bi);
  }
}
template<int LM>
__device__ __forceinline__ void h_cross(float (&sr)[16], float (&si)[16], int lane)
{
  const float sg = (lane & LM) ? -1.f : 1.f;
#pragma unroll
  for (int j=0;j<16;++j) {
    float pr=__shfl_xor(sr[j],LM,64), pi=__shfl_xor(si[j],LM,64);
    sr[j] = R0*fmaf(sg, sr[j], pr);
    si[j] = R0*fmaf(sg, si[j], pi);
  }
}
template<int W>
__device__ __forceinline__ void h_wire(float (&sr)[16], float (&si)[16], int lane)
{
  if constexpr (W < 6) h_cross<(1<<(5-W))>(sr,si,lane);
  else                 h_local<(1<<(9-W))>(sr,si);
}

// SX*H = r * [[1, i],[1, -i]]  (constants folded by compiler in local path)
template<int W>
__device__ __forceinline__ void sxh_wire(float (&sr)[16], float (&si)[16], int lane)
{
  if constexpr (W < 6) gen_cross<(1<<(5-W))>(sr,si,lane, R0,0.f, 0.f,R0, R0,0.f, 0.f,-R0);
  else                 gen_local<(1<<(9-W))>(sr,si,      R0,0.f, 0.f,R0, R0,0.f, 0.f,-R0);
}

// ---------------- CNOT ring -------------------------------------------------

// control lane bit0 (wire5), target local bit3 (wire6)
__device__ __forceinline__ void cnot_lane_local8(float (&sr)[16], float (&si)[16], int lane)
{
  const bool c = (lane & 1) != 0;
#pragma unroll
  for (int j=0;j<8;++j) {
    const int j1=j|8;
    float ar=sr[j], br=sr[j1];
    sr[j]=c?br:ar; sr[j1]=c?ar:br;
    float ai=si[j], bi=si[j1];
    si[j]=c?bi:ai; si[j1]=c?ai:bi;
  }
}
// both local: compile-time register swap (free after renaming)
template<int CM,int TM>
__device__ __forceinline__ void cnot_local(float (&sr)[16], float (&si)[16])
{
#pragma unroll
  for (int j=0;j<16;++j) if ((j&CM) && !(j&TM)) {
    const int j1=j|TM;
    float t=sr[j]; sr[j]=sr[j1]; sr[j1]=t;
    t=si[j]; si[j]=si[j1]; si[j1]=t;
  }
}
// control local bit0 (wire9), target lane bit5 (wire0)
__device__ __forceinline__ void cnot_local_lane(float (&sr)[16], float (&si)[16])
{
#pragma unroll
  for (int j=1;j<16;j+=2) {
    sr[j]=__shfl_xor(sr[j],32,64);
    si[j]=__shfl_xor(si[j],32,64);
  }
}

__device__ __forceinline__ void cnot_ring(float (&sr)[16], float (&si)[16], int lane)
{
  // CNOT(0,1)..(4,5): composed lane permutation, one bpermute round.
  // gather source lane = lane ^ (lane>>1)
  const int addr = (lane ^ (lane >> 1)) << 2;
#pragma unroll
  for (int j=0;j<16;++j) {
    sr[j] = __int_as_float(__builtin_amdgcn_ds_bpermute(addr, __float_as_int(sr[j])));
    si[j] = __int_as_float(__builtin_amdgcn_ds_bpermute(addr, __float_as_int(si[j])));
  }
  cnot_lane_local8(sr,si,lane);  // (5,6)
  cnot_local<8,4>(sr,si);        // (6,7)
  cnot_local<4,2>(sr,si);        // (7,8)
  cnot_local<2,1>(sr,si);        // (8,9)
  cnot_local_lane(sr,si);        // (9,0)
}

// ---------------- measurement ----------------------------------------------
// Writes 10 <Z> values for this sample to dst (and dst2 if non-null).
__device__ __forceinline__ void measure_store(const float (&sr)[16], const float (&si)[16],
                                              int lane, float* dst, float* dst2)
{
  float p[16];
#pragma unroll
  for (int j=0;j<16;++j) p[j] = fmaf(sr[j],sr[j], si[j]*si[j]);

  // j-tree: signed sums over local bits (wires 6..9) + total P
  float a[8]; float q9 = 0.f;
#pragma unroll
  for (int m=0;m<8;++m){ a[m] = p[2*m] + p[2*m+1]; q9 += p[2*m] - p[2*m+1]; }
  float bb[4]; float q8 = 0.f;
#pragma unroll
  for (int m=0;m<4;++m){ bb[m] = a[2*m] + a[2*m+1]; q8 += a[2*m] - a[2*m+1]; }
  float c0 = bb[0]+bb[1], c1 = bb[2]+bb[3];
  float q7 = (bb[0]-bb[1]) + (bb[2]-bb[3]);
  float q6 = c0 - c1;
  float P  = c0 + c1;

  // Walsh-Hadamard over lanes: after 6 stages lane l holds
  // sum_x P(x) * (-1)^{popcount(l & x)}.  Z_w (w<6) = coeff at l = 1<<(5-w).
  float v = P;
#pragma unroll
  for (int st=0; st<6; ++st) {
    const int m = 1<<st;
    float partner = __shfl_xor(v, m, 64);
    v = (lane & m) ? (partner - v) : (partner + v);
  }

  // plain butterflies for the 4 local sums
#pragma unroll
  for (int m=1;m<64;m<<=1) {
    q6 += __shfl_xor(q6,m,64); q7 += __shfl_xor(q7,m,64);
    q8 += __shfl_xor(q8,m,64); q9 += __shfl_xor(q9,m,64);
  }

  if (lane==32){ dst[0]=v; if(dst2) dst2[0]=v; }
  if (lane==16){ dst[1]=v; if(dst2) dst2[1]=v; }
  if (lane== 8){ dst[2]=v; if(dst2) dst2[2]=v; }
  if (lane== 4){ dst[3]=v; if(dst2) dst2[3]=v; }
  if (lane== 2){ dst[4]=v; if(dst2) dst2[4]=v; }
  if (lane== 1){ dst[5]=v; if(dst2) dst2[5]=v; }
  if (lane== 0){
    dst[6]=q6; dst[7]=q7; dst[8]=q8; dst[9]=q9;
    if (dst2){ dst2[6]=q6; dst2[7]=q7; dst2[8]=q8; dst2[9]=q9; }
  }
}

// ---------------- kernels --------------------------------------------------

// xq = x @ qlin_w.T + qlin_b, LDS-staged + per-block BN partial sums
__global__ __launch_bounds__(320) void k_xq(const float* __restrict__ x,
                     const float* __restrict__ w, const float* __restrict__ b,
                     float* __restrict__ xq, float* __restrict__ ps1, float* __restrict__ ps2)
{
  __shared__ float wlds[40*41];   // padded stride 41 to break bank conflicts
  __shared__ float xlds[320];
  __shared__ float accs[320];
  const int t = threadIdx.x;
  const int sl = t/40, f = t - sl*40;
  const int s0 = blockIdx.x*8;
#pragma unroll
  for (int i=0;i<5;++i) {
    int idx = t + i*320;
    int ff = idx/40, kk = idx - ff*40;
    wlds[ff*41+kk] = w[idx];
  }
  xlds[t] = x[s0*40 + t];
  __syncthreads();
  float acc = b[f];
#pragma unroll
  for (int k=0;k<40;++k) acc = fmaf(xlds[sl*40+k], wlds[f*41+k], acc);
  xq[s0*40 + t] = acc;
  accs[t] = acc;
  __syncthreads();
  if (t < 40) {
    float s1=0.f, s2=0.f;
#pragma unroll
    for (int m=0;m<8;++m){ float vv=accs[m*40+t]; s1+=vv; s2=fmaf(vv,vv,s2); }
    ps1[t*1024 + blockIdx.x] = s1;
    ps2[t*1024 + blockIdx.x] = s2;
  }
}

// reduce partials -> bn_a, bn_c   (grid 40 blocks, one per feature)
__global__ void k_bn(const float* __restrict__ ps1, const float* __restrict__ ps2,
                     const float* __restrict__ gamma, const float* __restrict__ beta,
                     float* __restrict__ bn_a, float* __restrict__ bn_c)
{
  const int f = blockIdx.x, t = threadIdx.x;
  float s1=0.f, s2=0.f;
#pragma unroll
  for (int i=0;i<4;++i){ s1 += ps1[f*1024 + t + i*256]; s2 += ps2[f*1024 + t + i*256]; }
  __shared__ float a1[256], a2[256];
  a1[t]=s1; a2[t]=s2; __syncthreads();
  for (int off=128; off; off>>=1){
    if (t<off){ a1[t]+=a1[t+off]; a2[t]+=a2[t+off]; }
    __syncthreads();
  }
  if (t==0) {
    float mu = a1[0]*(1.f/8192.f);
    float var = a2[0]*(1.f/8192.f) - mu*mu;
    float a = gamma[f]*rsqrtf(var + 1e-5f);
    bn_a[f]=a; bn_c[f]=beta[f]-mu*a;
  }
}

// fused param gates U = Rz(rz2)*Ry(ry1)*Rz(rz1) per (block,wire)
__global__ void k_consts(const float* __restrict__ rz1, const float* __restrict__ ry1,
                         const float* __restrict__ rz2, float* __restrict__ gates)
{
  int t = threadIdx.x;
  if (t < 40) {
    float g = rz1[t], a = ry1[t], b = rz2[t];
    float ca, sa, cp, sp, cm, sm;
    sincosf(0.5f*a, &sa, &ca);
    sincosf(0.5f*(b+g), &sp, &cp);
    sincosf(0.5f*(b-g), &sm, &cm);
    float* G = gates + t*8;
    G[0]= ca*cp; G[1]=-ca*sp;   // U00 = ca e^{-i(b+g)/2}
    G[2]=-sa*cm; G[3]= sa*sm;   // U01 = -sa e^{-i(b-g)/2}
    G[4]= sa*cm; G[5]= sa*sm;   // U10 =  sa e^{ i(b-g)/2}
    G[6]= ca*cp; G[7]= ca*sp;   // U11 = ca e^{ i(b+g)/2}
  }
}

#define GEN10(PTR) \
  gen_wire<0>(sr,si,lane,(PTR)+0);  gen_wire<1>(sr,si,lane,(PTR)+8);  \
  gen_wire<2>(sr,si,lane,(PTR)+16); gen_wire<3>(sr,si,lane,(PTR)+24); \
  gen_wire<4>(sr,si,lane,(PTR)+32); gen_wire<5>(sr,si,lane,(PTR)+40); \
  gen_wire<6>(sr,si,lane,(PTR)+48); gen_wire<7>(sr,si,lane,(PTR)+56); \
  gen_wire<8>(sr,si,lane,(PTR)+64); gen_wire<9>(sr,si,lane,(PTR)+72);

__global__ __launch_bounds__(256, 6) void k_qnn(const float* __restrict__ xq,
    const float* __restrict__ bn_a, const float* __restrict__ bn_c,
    const float* __restrict__ gates, float* __restrict__ x1)
{
  const int lane = threadIdx.x & 63;
  const int wv   = threadIdx.x >> 6;
  const int s    = blockIdx.x*4 + wv;

  __shared__ float Ebuf[4][10][8];
  __shared__ float Fbuf[4][3][10][8];

  // ---- per-sample fused encoder matrix per wire: Rx(f3) Rz(f2) Ry(f1) Rx(f0)
  if (lane < 10) {
    const int i = lane;
    const int f = 4*i;
    float h0 = 0.5f * fmaf(xq[s*40+f+0], bn_a[f+0], bn_c[f+0]);
    float h1 = 0.5f * fmaf(xq[s*40+f+1], bn_a[f+1], bn_c[f+1]);
    float h2 = 0.5f * fmaf(xq[s*40+f+2], bn_a[f+2], bn_c[f+2]);
    float h3 = 0.5f * fmaf(xq[s*40+f+3], bn_a[f+3], bn_c[f+3]);
    float c0,s0,c1,s1,c2,s2,c3,s3;
    sincosf(h0,&s0,&c0); sincosf(h1,&s1,&c1);
    sincosf(h2,&s2,&c2); sincosf(h3,&s3,&c3);
    // A = Ry(f1) * Rx(f0)
    float A00r=c1*c0, A00i= s1*s0;
    float A01r=-s1*c0, A01i=-c1*s0;
    float A10r= s1*c0, A10i=-c1*s0;
    float A11r= c1*c0, A11i=-s1*s0;
    // B = Rz(f2)*A
    float B00r = A00r*c2 + A00i*s2, B00i = A00i*c2 - A00r*s2;
    float B01r = A01r*c2 + A01i*s2, B01i = A01i*c2 - A01r*s2;
    float B10r = A10r*c2 - A10i*s2, B10i = A10i*c2 + A10r*s2;
    float B11r = A11r*c2 - A11i*s2, B11i = A11i*c2 + A11r*s2;
    // E = Rx(f3)*B
    float* e = &Ebuf[wv][i][0];
    e[0] = c3*B00r + s3*B10i;  e[1] = c3*B00i - s3*B10r;
    e[2] = c3*B01r + s3*B11i;  e[3] = c3*B01i - s3*B11r;
    e[4] = c3*B10r + s3*B00i;  e[5] = c3*B10i - s3*B00r;
    e[6] = c3*B11r + s3*B01i;  e[7] = c3*B11i - s3*B01r;
  }
  __syncthreads();

  // ---- fused F_k = U_{k+1} * E  (30 lanes, one 2x2 complex product each)
  if (lane < 30) {
    const int k = lane/10, i = lane - k*10;
    const float* U = gates + (k+1)*80 + i*8;
    const float* E = &Ebuf[wv][i][0];
    float u00r=U[0],u00i=U[1],u01r=U[2],u01i=U[3],u10r=U[4],u10i=U[5],u11r=U[6],u11i=U[7];
    float e00r=E[0],e00i=E[1],e01r=E[2],e01i=E[3],e10r=E[4],e10i=E[5],e11r=E[6],e11i=E[7];
    float* F = &Fbuf[wv][k][i][0];
    F[0] = u00r*e00r - u00i*e00i + u01r*e10r - u01i*e10i;
    F[1] = u00r*e00i + u00i*e00r + u01r*e10i + u01i*e10r;
    F[2] = u00r*e01r - u00i*e01i + u01r*e11r - u01i*e11i;
    F[3] = u00r*e01i + u00i*e01r + u01r*e11i + u01i*e11r;
    F[4] = u10r*e00r - u10i*e00i + u11r*e10r - u11i*e10i;
    F[5] = u10r*e00i + u10i*e00r + u11r*e10i + u11i*e10r;
    F[6] = u10r*e01r - u10i*e01i + u11r*e11r - u11i*e11i;
    F[7] = u10r*e01i + u10i*e01r + u11r*e11i + u11i*e11r;
  }
  __syncthreads();

  // ---- init: state = U0 |0..0>  (product state, column 0 per wire)
  float sr[16], si[16];
  {
    // cross-wire factor (wires 0..5, lane bits 5..0)
    float cr = 1.f, ci = 0.f;
#pragma unroll
    for (int w=0; w<6; ++w) {
      const float g0r = gates[w*8+0], g0i = gates[w*8+1];
      const float g1r = gates[w*8+4], g1i = gates[w*8+5];
      const bool bset = (lane >> (5-w)) & 1;
      const float ar = bset ? g1r : g0r, ai = bset ? g1i : g0i;
      const float tr = cr*ar - ci*ai, ti = cr*ai + ci*ar;
      cr = tr; ci = ti;
    }
    // local pair products
    float p67r[4], p67i[4], p89r[4], p89i[4];
#pragma unroll
    for (int b6=0;b6<2;++b6)
#pragma unroll
      for (int b7=0;b7<2;++b7) {
        const float x6r = gates[6*8 + 4*b6], x6i = gates[6*8 + 4*b6 + 1];
        const float x7r = gates[7*8 + 4*b7], x7i = gates[7*8 + 4*b7 + 1];
        p67r[b6*2+b7] = x6r*x7r - x6i*x7i;
        p67i[b6*2+b7] = x6r*x7i + x6i*x7r;
      }
#pragma unroll
    for (int b8=0;b8<2;++b8)
#pragma unroll
      for (int b9=0;b9<2;++b9) {
        const float x8r = gates[8*8 + 4*b8], x8i = gates[8*8 + 4*b8 + 1];
        const float x9r = gates[9*8 + 4*b9], x9i = gates[9*8 + 4*b9 + 1];
        p89r[b8*2+b9] = x8r*x9r - x8i*x9i;
        p89i[b8*2+b9] = x8r*x9i + x8i*x9r;
      }
    // fold cross factor into p67
#pragma unroll
    for (int m=0;m<4;++m) {
      const float tr = p67r[m]*cr - p67i[m]*ci;
      const float ti = p67r[m]*ci + p67i[m]*cr;
      p67r[m]=tr; p67i[m]=ti;
    }
#pragma unroll
    for (int j=0;j<16;++j) {
      const int hi = j>>2, lo = j&3;    // (b6,b7) , (b8,b9)
      sr[j] = p67r[hi]*p89r[lo] - p67i[hi]*p89i[lo];
      si[j] = p67r[hi]*p89i[lo] + p67i[hi]*p89r[lo];
    }
  }

  // ---- main circuit: 4 rings interleaved with 3 fused layers
  cnot_ring(sr,si,lane);
  { const float* F = &Fbuf[wv][0][0][0]; GEN10(F) }
  cnot_ring(sr,si,lane);
  { const float* F = &Fbuf[wv][1][0][0]; GEN10(F) }
  cnot_ring(sr,si,lane);
  { const float* F = &Fbuf[wv][2][0][0]; GEN10(F) }
  cnot_ring(sr,si,lane);

  float* dst = x1 + s*40;
  measure_store(sr,si,lane,dst,nullptr);

  // H on all wires
  h_wire<0>(sr,si,lane); h_wire<1>(sr,si,lane); h_wire<2>(sr,si,lane);
  h_wire<3>(sr,si,lane); h_wire<4>(sr,si,lane); h_wire<5>(sr,si,lane);
  h_wire<6>(sr,si,lane); h_wire<7>(sr,si,lane); h_wire<8>(sr,si,lane);
  h_wire<9>(sr,si,lane);
  measure_store(sr,si,lane,dst+10,nullptr);

  // SX*H on all wires; rz3 is diagonal -> outs[3] == outs[2]
  sxh_wire<0>(sr,si,lane); sxh_wire<1>(sr,si,lane); sxh_wire<2>(sr,si,lane);
  sxh_wire<3>(sr,si,lane); sxh_wire<4>(sr,si,lane); sxh_wire<5>(sr,si,lane);
  sxh_wire<6>(sr,si,lane); sxh_wire<7>(sr,si,lane); sxh_wire<8>(sr,si,lane);
  sxh_wire<9>(sr,si,lane);
  measure_store(sr,si,lane,dst+20,dst+30);
}

// epilogue: x2 = relu(x@clin_w.T+clin_b); out = [x1,x2]@lin_w.T + lin_b
__global__ void k_epi(const float* __restrict__ x, const float* __restrict__ x1,
                      const float* __restrict__ clin_w, const float* __restrict__ clin_b,
                      const float* __restrict__ lin_w, const float* __restrict__ lin_b,
                      float* __restrict__ out)
{
  const int t = threadIdx.x;
  const int sl = t/40, f = t - sl*40;
  const int s = blockIdx.x*8 + sl;
  __shared__ float x2s[8][40];
  float acc = clin_b[f];
#pragma unroll
  for (int k=0;k<40;++k) acc = fmaf(x[s*40+k], clin_w[f*40+k], acc);
  x2s[sl][f] = fmaxf(acc, 0.f);
  __syncthreads();
  float o = lin_b[f];
#pragma unroll
  for (int j=0;j<40;++j) o = fmaf(x1[s*40+j], lin_w[f*80+j], o);
#pragma unroll
  for (int j=0;j<40;++j) o = fmaf(x2s[sl][j], lin_w[f*80+40+j], o);
  out[s*40+f] = o;
}

// ---------------- launch ---------------------------------------------------
extern "C" void kernel_launch(void* const* d_in, const int* in_sizes, int n_in,
                              void* d_out, int out_size, void* d_ws, size_t ws_size,
                              hipStream_t stream)
{
  const float* x      = (const float*)d_in[0];
  const float* qlin_w = (const float*)d_in[1];
  const float* qlin_b = (const float*)d_in[2];
  const float* bn_g   = (const float*)d_in[3];
  const float* bn_b   = (const float*)d_in[4];
  const float* clin_w = (const float*)d_in[5];
  const float* clin_b = (const float*)d_in[6];
  const float* lin_w  = (const float*)d_in[7];
  const float* lin_b  = (const float*)d_in[8];
  const float* rz1    = (const float*)d_in[9];
  const float* ry1    = (const float*)d_in[10];
  const float* rz2    = (const float*)d_in[11];

  float* ws    = (float*)d_ws;
  float* xq    = ws + WS_XQ;
  float* x1    = ws + WS_X1;
  float* ps1   = ws + WS_PS1;
  float* ps2   = ws + WS_PS2;
  float* bn_a  = ws + WS_BNA;
  float* bn_c  = ws + WS_BNC;
  float* gates = ws + WS_GATES;
  float* out   = (float*)d_out;

  hipLaunchKernelGGL(k_consts, dim3(1),    dim3(64),  0, stream, rz1, ry1, rz2, gates);
  hipLaunchKernelGGL(k_xq,     dim3(1024), dim3(320), 0, stream, x, qlin_w, qlin_b, xq, ps1, ps2);
  hipLaunchKernelGGL(k_bn,     dim3(40),   dim3(256), 0, stream, ps1, ps2, bn_g, bn_b, bn_a, bn_c);
  hipLaunchKernelGGL(k_qnn,    dim3(2048), dim3(256), 0, stream, xq, bn_a, bn_c, gates, x1);
  hipLaunchKernelGGL(k_epi,    dim3(1024), dim3(320), 0, stream, x, x1, clin_w, clin_b, lin_w, lin_b, out);
}

// Round 3
// 503.377 us; speedup vs baseline: 1.8439x; 1.8439x over previous
//
#include <hip/hip_runtime.h>
#include <math.h>

// ---------------------------------------------------------------------------
// QINRLayer: Linear+BN -> 10-qubit QNN (statevector sim) -> classical branch
// One wave per sample; 1024 complex amps in registers (16/lane).
// k = lane*16 + j ; wire w (0=MSB) <-> lane bit (5-w) for w<6, j bit (9-w) else.
//
// Circuit algebra used (all exact):
//   U0|0..0> is a product state -> direct init, no gate pass.
//   encode(E) then param layer U_{k+1} fuse into F_k = U_{k+1} * E.
//   CNOTs (0,1)..(4,5) compose into lane perm  src = lane ^ (lane>>1).
//   rz3 is diagonal -> outs[3] == outs[2]; 4th measure dropped.
//
// R2 lesson: __launch_bounds__(256,6) capped VGPRs at ~85 -> statevector
// spilled to scratch (3.3 GB HBM traffic, 12% VALU). Keep >= 102 VGPR budget.
// ---------------------------------------------------------------------------

#define R0 0.70710678118654752f

// ws layout (floats)
#define WS_XQ    0         // 8192*40
#define WS_X1    327680    // 8192*40   (ps1/ps2 alias this region, consumed first)
#define WS_PS1   327680    // 40*1024
#define WS_PS2   368640    // 40*1024
#define WS_BNA   655360    // 40
#define WS_BNC   655400    // 40
#define WS_GATES 655440    // 40 gates * 8 floats (fused rz2*ry1*rz1 per block,wire)

// ---------------- gate primitives (state in registers) ---------------------

template<int M>
__device__ __forceinline__ void gen_local(float (&sr)[16], float (&si)[16],
    float g00r,float g00i,float g01r,float g01i,
    float g10r,float g10i,float g11r,float g11i)
{
#pragma unroll
  for (int j=0;j<16;++j) if (!(j&M)) {
    const int j1=j|M;
    float ar=sr[j],ai=si[j],br=sr[j1],bi=si[j1];
    sr[j]  = g00r*ar - g00i*ai + g01r*br - g01i*bi;
    si[j]  = g00r*ai + g00i*ar + g01r*bi + g01i*br;
    sr[j1] = g10r*ar - g10i*ai + g11r*br - g11i*bi;
    si[j1] = g10r*ai + g10i*ar + g11r*bi + g11i*br;
  }
}

template<int LM>
__device__ __forceinline__ void gen_cross(float (&sr)[16], float (&si)[16], int lane,
    float g00r,float g00i,float g01r,float g01i,
    float g10r,float g10i,float g11r,float g11i)
{
  const bool hi = (lane & LM) != 0;
  const float gar = hi ? g11r : g00r;
  const float gai = hi ? g11i : g00i;
  const float gbr = hi ? g10r : g01r;
  const float gbi = hi ? g10i : g01i;
#pragma unroll
  for (int j=0;j<16;++j) {
    float pr = __shfl_xor(sr[j], LM, 64);
    float pi = __shfl_xor(si[j], LM, 64);
    float mr = sr[j], mi = si[j];
    sr[j] = gar*mr - gai*mi + gbr*pr - gbi*pi;
    si[j] = gar*mi + gai*mr + gbr*pi + gbi*pr;
  }
}

template<int W>
__device__ __forceinline__ void gen_wire(float (&sr)[16], float (&si)[16], int lane,
                                         const float* g)
{
  float g00r=g[0],g00i=g[1],g01r=g[2],g01i=g[3],g10r=g[4],g10i=g[5],g11r=g[6],g11i=g[7];
  if constexpr (W < 6) gen_cross<(1<<(5-W))>(sr,si,lane,g00r,g00i,g01r,g01i,g10r,g10i,g11r,g11i);
  else                 gen_local<(1<<(9-W))>(sr,si,g00r,g00i,g01r,g01i,g10r,g10i,g11r,g11i);
}

// Hadamard
template<int M>
__device__ __forceinline__ void h_local(float (&sr)[16], float (&si)[16])
{
#pragma unroll
  for (int j=0;j<16;++j) if (!(j&M)) {
    const int j1=j|M;
    float ar=sr[j],ai=si[j],br=sr[j1],bi=si[j1];
    sr[j]=R0*(ar+br);  si[j]=R0*(ai+bi);
    sr[j1]=R0*(ar-br); si[j1]=R0*(ai-bi);
  }
}
template<int LM>
__device__ __forceinline__ void h_cross(float (&sr)[16], float (&si)[16], int lane)
{
  const float sg = (lane & LM) ? -1.f : 1.f;
#pragma unroll
  for (int j=0;j<16;++j) {
    float pr=__shfl_xor(sr[j],LM,64), pi=__shfl_xor(si[j],LM,64);
    sr[j] = R0*fmaf(sg, sr[j], pr);
    si[j] = R0*fmaf(sg, si[j], pi);
  }
}
template<int W>
__device__ __forceinline__ void h_wire(float (&sr)[16], float (&si)[16], int lane)
{
  if constexpr (W < 6) h_cross<(1<<(5-W))>(sr,si,lane);
  else                 h_local<(1<<(9-W))>(sr,si);
}

// SX*H = r * [[1, i],[1, -i]]
template<int W>
__device__ __forceinline__ void sxh_wire(float (&sr)[16], float (&si)[16], int lane)
{
  if constexpr (W < 6) gen_cross<(1<<(5-W))>(sr,si,lane, R0,0.f, 0.f,R0, R0,0.f, 0.f,-R0);
  else                 gen_local<(1<<(9-W))>(sr,si,      R0,0.f, 0.f,R0, R0,0.f, 0.f,-R0);
}

// ---------------- CNOT ring -------------------------------------------------

// control lane bit0 (wire5), target local bit3 (wire6)
__device__ __forceinline__ void cnot_lane_local8(float (&sr)[16], float (&si)[16], int lane)
{
  const bool c = (lane & 1) != 0;
#pragma unroll
  for (int j=0;j<8;++j) {
    const int j1=j|8;
    float ar=sr[j], br=sr[j1];
    sr[j]=c?br:ar; sr[j1]=c?ar:br;
    float ai=si[j], bi=si[j1];
    si[j]=c?bi:ai; si[j1]=c?ai:bi;
  }
}
// both local: compile-time register swap (free after renaming)
template<int CM,int TM>
__device__ __forceinline__ void cnot_local(float (&sr)[16], float (&si)[16])
{
#pragma unroll
  for (int j=0;j<16;++j) if ((j&CM) && !(j&TM)) {
    const int j1=j|TM;
    float t=sr[j]; sr[j]=sr[j1]; sr[j1]=t;
    t=si[j]; si[j]=si[j1]; si[j1]=t;
  }
}
// control local bit0 (wire9), target lane bit5 (wire0)
__device__ __forceinline__ void cnot_local_lane(float (&sr)[16], float (&si)[16])
{
#pragma unroll
  for (int j=1;j<16;j+=2) {
    sr[j]=__shfl_xor(sr[j],32,64);
    si[j]=__shfl_xor(si[j],32,64);
  }
}

__device__ __forceinline__ void cnot_ring(float (&sr)[16], float (&si)[16], int lane)
{
  // CNOT(0,1)..(4,5): composed lane permutation, one bpermute round.
  const int addr = (lane ^ (lane >> 1)) << 2;
#pragma unroll
  for (int j=0;j<16;++j) {
    sr[j] = __int_as_float(__builtin_amdgcn_ds_bpermute(addr, __float_as_int(sr[j])));
    si[j] = __int_as_float(__builtin_amdgcn_ds_bpermute(addr, __float_as_int(si[j])));
  }
  cnot_lane_local8(sr,si,lane);  // (5,6)
  cnot_local<8,4>(sr,si);        // (6,7)
  cnot_local<4,2>(sr,si);        // (7,8)
  cnot_local<2,1>(sr,si);        // (8,9)
  cnot_local_lane(sr,si);        // (9,0)
}

// ---------------- measurement ----------------------------------------------
__device__ __forceinline__ void measure_store(const float (&sr)[16], const float (&si)[16],
                                              int lane, float* dst, float* dst2)
{
  float p[16];
#pragma unroll
  for (int j=0;j<16;++j) p[j] = fmaf(sr[j],sr[j], si[j]*si[j]);

  // j-tree: signed sums over local bits (wires 6..9) + total P
  float a[8]; float q9 = 0.f;
#pragma unroll
  for (int m=0;m<8;++m){ a[m] = p[2*m] + p[2*m+1]; q9 += p[2*m] - p[2*m+1]; }
  float bb[4]; float q8 = 0.f;
#pragma unroll
  for (int m=0;m<4;++m){ bb[m] = a[2*m] + a[2*m+1]; q8 += a[2*m] - a[2*m+1]; }
  float c0 = bb[0]+bb[1], c1 = bb[2]+bb[3];
  float q7 = (bb[0]-bb[1]) + (bb[2]-bb[3]);
  float q6 = c0 - c1;
  float P  = c0 + c1;

  // Walsh-Hadamard over lanes: lane l ends with sum_x P(x)(-1)^{popcount(l&x)}
  float v = P;
#pragma unroll
  for (int st=0; st<6; ++st) {
    const int m = 1<<st;
    float partner = __shfl_xor(v, m, 64);
    v = (lane & m) ? (partner - v) : (partner + v);
  }

#pragma unroll
  for (int m=1;m<64;m<<=1) {
    q6 += __shfl_xor(q6,m,64); q7 += __shfl_xor(q7,m,64);
    q8 += __shfl_xor(q8,m,64); q9 += __shfl_xor(q9,m,64);
  }

  if (lane==32){ dst[0]=v; if(dst2) dst2[0]=v; }
  if (lane==16){ dst[1]=v; if(dst2) dst2[1]=v; }
  if (lane== 8){ dst[2]=v; if(dst2) dst2[2]=v; }
  if (lane== 4){ dst[3]=v; if(dst2) dst2[3]=v; }
  if (lane== 2){ dst[4]=v; if(dst2) dst2[4]=v; }
  if (lane== 1){ dst[5]=v; if(dst2) dst2[5]=v; }
  if (lane== 0){
    dst[6]=q6; dst[7]=q7; dst[8]=q8; dst[9]=q9;
    if (dst2){ dst2[6]=q6; dst2[7]=q7; dst2[8]=q8; dst2[9]=q9; }
  }
}

// ---------------- kernels --------------------------------------------------

__global__ __launch_bounds__(320) void k_xq(const float* __restrict__ x,
                     const float* __restrict__ w, const float* __restrict__ b,
                     float* __restrict__ xq, float* __restrict__ ps1, float* __restrict__ ps2)
{
  __shared__ float wlds[40*41];
  __shared__ float xlds[320];
  __shared__ float accs[320];
  const int t = threadIdx.x;
  const int sl = t/40, f = t - sl*40;
  const int s0 = blockIdx.x*8;
#pragma unroll
  for (int i=0;i<5;++i) {
    int idx = t + i*320;
    int ff = idx/40, kk = idx - ff*40;
    wlds[ff*41+kk] = w[idx];
  }
  xlds[t] = x[s0*40 + t];
  __syncthreads();
  float acc = b[f];
#pragma unroll
  for (int k=0;k<40;++k) acc = fmaf(xlds[sl*40+k], wlds[f*41+k], acc);
  xq[s0*40 + t] = acc;
  accs[t] = acc;
  __syncthreads();
  if (t < 40) {
    float s1=0.f, s2=0.f;
#pragma unroll
    for (int m=0;m<8;++m){ float vv=accs[m*40+t]; s1+=vv; s2=fmaf(vv,vv,s2); }
    ps1[t*1024 + blockIdx.x] = s1;
    ps2[t*1024 + blockIdx.x] = s2;
  }
}

__global__ void k_bn(const float* __restrict__ ps1, const float* __restrict__ ps2,
                     const float* __restrict__ gamma, const float* __restrict__ beta,
                     float* __restrict__ bn_a, float* __restrict__ bn_c)
{
  const int f = blockIdx.x, t = threadIdx.x;
  float s1=0.f, s2=0.f;
#pragma unroll
  for (int i=0;i<4;++i){ s1 += ps1[f*1024 + t + i*256]; s2 += ps2[f*1024 + t + i*256]; }
  __shared__ float a1[256], a2[256];
  a1[t]=s1; a2[t]=s2; __syncthreads();
  for (int off=128; off; off>>=1){
    if (t<off){ a1[t]+=a1[t+off]; a2[t]+=a2[t+off]; }
    __syncthreads();
  }
  if (t==0) {
    float mu = a1[0]*(1.f/8192.f);
    float var = a2[0]*(1.f/8192.f) - mu*mu;
    float a = gamma[f]*rsqrtf(var + 1e-5f);
    bn_a[f]=a; bn_c[f]=beta[f]-mu*a;
  }
}

__global__ void k_consts(const float* __restrict__ rz1, const float* __restrict__ ry1,
                         const float* __restrict__ rz2, float* __restrict__ gates)
{
  int t = threadIdx.x;
  if (t < 40) {
    float g = rz1[t], a = ry1[t], b = rz2[t];
    float ca, sa, cp, sp, cm, sm;
    sincosf(0.5f*a, &sa, &ca);
    sincosf(0.5f*(b+g), &sp, &cp);
    sincosf(0.5f*(b-g), &sm, &cm);
    float* G = gates + t*8;
    G[0]= ca*cp; G[1]=-ca*sp;
    G[2]=-sa*cm; G[3]= sa*sm;
    G[4]= sa*cm; G[5]= sa*sm;
    G[6]= ca*cp; G[7]= ca*sp;
  }
}

#define GEN10(PTR) \
  gen_wire<0>(sr,si,lane,(PTR)+0);  gen_wire<1>(sr,si,lane,(PTR)+8);  \
  gen_wire<2>(sr,si,lane,(PTR)+16); gen_wire<3>(sr,si,lane,(PTR)+24); \
  gen_wire<4>(sr,si,lane,(PTR)+32); gen_wire<5>(sr,si,lane,(PTR)+40); \
  gen_wire<6>(sr,si,lane,(PTR)+48); gen_wire<7>(sr,si,lane,(PTR)+56); \
  gen_wire<8>(sr,si,lane,(PTR)+64); gen_wire<9>(sr,si,lane,(PTR)+72);

// NOTE: min-waves arg deliberately 5 (<=102 VGPR). 6 forced spill in R2.
__global__ __launch_bounds__(256, 5) void k_qnn(const float* __restrict__ xq,
    const float* __restrict__ bn_a, const float* __restrict__ bn_c,
    const float* __restrict__ gates, float* __restrict__ x1)
{
  const int lane = threadIdx.x & 63;
  const int wv   = threadIdx.x >> 6;
  const int s    = blockIdx.x*4 + wv;

  __shared__ float Ebuf[4][10][8];
  __shared__ float Fbuf[4][3][10][8];

  // ---- per-sample fused encoder matrix per wire: Rx(f3) Rz(f2) Ry(f1) Rx(f0)
  if (lane < 10) {
    const int i = lane;
    const int f = 4*i;
    float h0 = 0.5f * fmaf(xq[s*40+f+0], bn_a[f+0], bn_c[f+0]);
    float h1 = 0.5f * fmaf(xq[s*40+f+1], bn_a[f+1], bn_c[f+1]);
    float h2 = 0.5f * fmaf(xq[s*40+f+2], bn_a[f+2], bn_c[f+2]);
    float h3 = 0.5f * fmaf(xq[s*40+f+3], bn_a[f+3], bn_c[f+3]);
    float c0,s0,c1,s1,c2,s2,c3,s3;
    sincosf(h0,&s0,&c0); sincosf(h1,&s1,&c1);
    sincosf(h2,&s2,&c2); sincosf(h3,&s3,&c3);
    float A00r=c1*c0, A00i= s1*s0;
    float A01r=-s1*c0, A01i=-c1*s0;
    float A10r= s1*c0, A10i=-c1*s0;
    float A11r= c1*c0, A11i=-s1*s0;
    float B00r = A00r*c2 + A00i*s2, B00i = A00i*c2 - A00r*s2;
    float B01r = A01r*c2 + A01i*s2, B01i = A01i*c2 - A01r*s2;
    float B10r = A10r*c2 - A10i*s2, B10i = A10i*c2 + A10r*s2;
    float B11r = A11r*c2 - A11i*s2, B11i = A11i*c2 + A11r*s2;
    float* e = &Ebuf[wv][i][0];
    e[0] = c3*B00r + s3*B10i;  e[1] = c3*B00i - s3*B10r;
    e[2] = c3*B01r + s3*B11i;  e[3] = c3*B01i - s3*B11r;
    e[4] = c3*B10r + s3*B00i;  e[5] = c3*B10i - s3*B00r;
    e[6] = c3*B11r + s3*B01i;  e[7] = c3*B11i - s3*B01r;
  }
  __syncthreads();

  // ---- fused F_k = U_{k+1} * E  (30 lanes, one 2x2 complex product each)
  if (lane < 30) {
    const int k = lane/10, i = lane - k*10;
    const float* U = gates + (k+1)*80 + i*8;
    const float* E = &Ebuf[wv][i][0];
    float u00r=U[0],u00i=U[1],u01r=U[2],u01i=U[3],u10r=U[4],u10i=U[5],u11r=U[6],u11i=U[7];
    float e00r=E[0],e00i=E[1],e01r=E[2],e01i=E[3],e10r=E[4],e10i=E[5],e11r=E[6],e11i=E[7];
    float* F = &Fbuf[wv][k][i][0];
    F[0] = u00r*e00r - u00i*e00i + u01r*e10r - u01i*e10i;
    F[1] = u00r*e00i + u00i*e00r + u01r*e10i + u01i*e10r;
    F[2] = u00r*e01r - u00i*e01i + u01r*e11r - u01i*e11i;
    F[3] = u00r*e01i + u00i*e01r + u01r*e11i + u01i*e11r;
    F[4] = u10r*e00r - u10i*e00i + u11r*e10r - u11i*e10i;
    F[5] = u10r*e00i + u10i*e00r + u11r*e10i + u11i*e10r;
    F[6] = u10r*e01r - u10i*e01i + u11r*e11r - u11i*e11i;
    F[7] = u10r*e01i + u10i*e01r + u11r*e11i + u11i*e11r;
  }
  __syncthreads();

  // ---- init: state = U0 |0..0>  (product state, column 0 per wire)
  float sr[16], si[16];
  {
    float cr = 1.f, ci = 0.f;
#pragma unroll
    for (int w=0; w<6; ++w) {
      const float g0r = gates[w*8+0], g0i = gates[w*8+1];
      const float g1r = gates[w*8+4], g1i = gates[w*8+5];
      const bool bset = (lane >> (5-w)) & 1;
      const float ar = bset ? g1r : g0r, ai = bset ? g1i : g0i;
      const float tr = cr*ar - ci*ai, ti = cr*ai + ci*ar;
      cr = tr; ci = ti;
    }
    float p67r[4], p67i[4], p89r[4], p89i[4];
#pragma unroll
    for (int b6=0;b6<2;++b6)
#pragma unroll
      for (int b7=0;b7<2;++b7) {
        const float x6r = gates[6*8 + 4*b6], x6i = gates[6*8 + 4*b6 + 1];
        const float x7r = gates[7*8 + 4*b7], x7i = gates[7*8 + 4*b7 + 1];
        p67r[b6*2+b7] = x6r*x7r - x6i*x7i;
        p67i[b6*2+b7] = x6r*x7i + x6i*x7r;
      }
#pragma unroll
    for (int b8=0;b8<2;++b8)
#pragma unroll
      for (int b9=0;b9<2;++b9) {
        const float x8r = gates[8*8 + 4*b8], x8i = gates[8*8 + 4*b8 + 1];
        const float x9r = gates[9*8 + 4*b9], x9i = gates[9*8 + 4*b9 + 1];
        p89r[b8*2+b9] = x8r*x9r - x8i*x9i;
        p89i[b8*2+b9] = x8r*x9i + x8i*x9r;
      }
#pragma unroll
    for (int m=0;m<4;++m) {
      const float tr = p67r[m]*cr - p67i[m]*ci;
      const float ti = p67r[m]*ci + p67i[m]*cr;
      p67r[m]=tr; p67i[m]=ti;
    }
#pragma unroll
    for (int j=0;j<16;++j) {
      const int hi = j>>2, lo = j&3;
      sr[j] = p67r[hi]*p89r[lo] - p67i[hi]*p89i[lo];
      si[j] = p67r[hi]*p89i[lo] + p67i[hi]*p89r[lo];
    }
  }

  // ---- main circuit: 4 rings interleaved with 3 fused layers
  cnot_ring(sr,si,lane);
  { const float* F = &Fbuf[wv][0][0][0]; GEN10(F) }
  cnot_ring(sr,si,lane);
  { const float* F = &Fbuf[wv][1][0][0]; GEN10(F) }
  cnot_ring(sr,si,lane);
  { const float* F = &Fbuf[wv][2][0][0]; GEN10(F) }
  cnot_ring(sr,si,lane);

  float* dst = x1 + s*40;
  measure_store(sr,si,lane,dst,nullptr);

  h_wire<0>(sr,si,lane); h_wire<1>(sr,si,lane); h_wire<2>(sr,si,lane);
  h_wire<3>(sr,si,lane); h_wire<4>(sr,si,lane); h_wire<5>(sr,si,lane);
  h_wire<6>(sr,si,lane); h_wire<7>(sr,si,lane); h_wire<8>(sr,si,lane);
  h_wire<9>(sr,si,lane);
  measure_store(sr,si,lane,dst+10,nullptr);

  sxh_wire<0>(sr,si,lane); sxh_wire<1>(sr,si,lane); sxh_wire<2>(sr,si,lane);
  sxh_wire<3>(sr,si,lane); sxh_wire<4>(sr,si,lane); sxh_wire<5>(sr,si,lane);
  sxh_wire<6>(sr,si,lane); sxh_wire<7>(sr,si,lane); sxh_wire<8>(sr,si,lane);
  sxh_wire<9>(sr,si,lane);
  measure_store(sr,si,lane,dst+20,dst+30);
}

__global__ void k_epi(const float* __restrict__ x, const float* __restrict__ x1,
                      const float* __restrict__ clin_w, const float* __restrict__ clin_b,
                      const float* __restrict__ lin_w, const float* __restrict__ lin_b,
                      float* __restrict__ out)
{
  const int t = threadIdx.x;
  const int sl = t/40, f = t - sl*40;
  const int s = blockIdx.x*8 + sl;
  __shared__ float x2s[8][40];
  float acc = clin_b[f];
#pragma unroll
  for (int k=0;k<40;++k) acc = fmaf(x[s*40+k], clin_w[f*40+k], acc);
  x2s[sl][f] = fmaxf(acc, 0.f);
  __syncthreads();
  float o = lin_b[f];
#pragma unroll
  for (int j=0;j<40;++j) o = fmaf(x1[s*40+j], lin_w[f*80+j], o);
#pragma unroll
  for (int j=0;j<40;++j) o = fmaf(x2s[sl][j], lin_w[f*80+40+j], o);
  out[s*40+f] = o;
}

// ---------------- launch ---------------------------------------------------
extern "C" void kernel_launch(void* const* d_in, const int* in_sizes, int n_in,
                              void* d_out, int out_size, void* d_ws, size_t ws_size,
                              hipStream_t stream)
{
  const float* x      = (const float*)d_in[0];
  const float* qlin_w = (const float*)d_in[1];
  const float* qlin_b = (const float*)d_in[2];
  const float* bn_g   = (const float*)d_in[3];
  const float* bn_b   = (const float*)d_in[4];
  const float* clin_w = (const float*)d_in[5];
  const float* clin_b = (const float*)d_in[6];
  const float* lin_w  = (const float*)d_in[7];
  const float* lin_b  = (const float*)d_in[8];
  const float* rz1    = (const float*)d_in[9];
  const float* ry1    = (const float*)d_in[10];
  const float* rz2    = (const float*)d_in[11];

  float* ws    = (float*)d_ws;
  float* xq    = ws + WS_XQ;
  float* x1    = ws + WS_X1;
  float* ps1   = ws + WS_PS1;
  float* ps2   = ws + WS_PS2;
  float* bn_a  = ws + WS_BNA;
  float* bn_c  = ws + WS_BNC;
  float* gates = ws + WS_GATES;
  float* out   = (float*)d_out;

  hipLaunchKernelGGL(k_consts, dim3(1),    dim3(64),  0, stream, rz1, ry1, rz2, gates);
  hipLaunchKernelGGL(k_xq,     dim3(1024), dim3(320), 0, stream, x, qlin_w, qlin_b, xq, ps1, ps2);
  hipLaunchKernelGGL(k_bn,     dim3(40),   dim3(256), 0, stream, ps1, ps2, bn_g, bn_b, bn_a, bn_c);
  hipLaunchKernelGGL(k_qnn,    dim3(2048), dim3(256), 0, stream, xq, bn_a, bn_c, gates, x1);
  hipLaunchKernelGGL(k_epi,    dim3(1024), dim3(320), 0, stream, x, x1, clin_w, clin_b, lin_w, lin_b, out);
}

// Round 4
// 247.219 us; speedup vs baseline: 3.7545x; 2.0362x over previous
//
#include <hip/hip_runtime.h>
#include <math.h>

// ---------------------------------------------------------------------------
// QINRLayer: Linear+BN -> 10-qubit QNN (statevector sim) -> classical branch
// One wave per sample; 1024 complex amps in registers (16/lane).
// k = lane*16 + j ; wire w (0=MSB) <-> lane bit (5-w) for w<6, j bit (9-w) else.
//
// Circuit algebra (all exact):
//   U0|0..0> is a product state -> direct init, no gate pass.
//   encode(E) then param layer U_{k+1} fuse into F_k = U_{k+1} * E.
//   CNOTs (0,1)..(4,5) compose into lane perm  src = lane ^ (lane>>1).
//   rz3 is diagonal -> outs[3] == outs[2]; 4th measure dropped.
//
// HARD-WON: do NOT set a min-waves-per-EU in __launch_bounds__ on k_qnn.
//   R1: __launch_bounds__(256)   -> 88 VGPR, no spill, VALU 66%
//   R2: __launch_bounds__(256,6) -> 40 VGPR, state spilled, 3.3 GB HBM
//   R3: __launch_bounds__(256,5) -> 48 VGPR, state spilled, 1.7 GB HBM
// The waves-per-eu bound tips the allocator into a spill cascade even when
// the nominal budget fits. Leave it unset.
// ---------------------------------------------------------------------------

#define R0 0.70710678118654752f

// ws layout (floats)
#define WS_XQ    0         // 8192*40
#define WS_X1    327680    // 8192*40   (ps1/ps2 alias this region, consumed first)
#define WS_PS1   327680    // 40*1024
#define WS_PS2   368640    // 40*1024
#define WS_BNA   655360    // 40
#define WS_BNC   655400    // 40
#define WS_GATES 655440    // 40 gates * 8 floats (fused rz2*ry1*rz1 per block,wire)

// ---------------- gate primitives (state in registers) ---------------------

template<int M>
__device__ __forceinline__ void gen_local(float (&sr)[16], float (&si)[16],
    float g00r,float g00i,float g01r,float g01i,
    float g10r,float g10i,float g11r,float g11i)
{
#pragma unroll
  for (int j=0;j<16;++j) if (!(j&M)) {
    const int j1=j|M;
    float ar=sr[j],ai=si[j],br=sr[j1],bi=si[j1];
    sr[j]  = g00r*ar - g00i*ai + g01r*br - g01i*bi;
    si[j]  = g00r*ai + g00i*ar + g01r*bi + g01i*br;
    sr[j1] = g10r*ar - g10i*ai + g11r*br - g11i*bi;
    si[j1] = g10r*ai + g10i*ar + g11r*bi + g11i*br;
  }
}

template<int LM>
__device__ __forceinline__ void gen_cross(float (&sr)[16], float (&si)[16], int lane,
    float g00r,float g00i,float g01r,float g01i,
    float g10r,float g10i,float g11r,float g11i)
{
  const bool hi = (lane & LM) != 0;
  const float gar = hi ? g11r : g00r;
  const float gai = hi ? g11i : g00i;
  const float gbr = hi ? g10r : g01r;
  const float gbi = hi ? g10i : g01i;
#pragma unroll
  for (int j=0;j<16;++j) {
    float pr = __shfl_xor(sr[j], LM, 64);
    float pi = __shfl_xor(si[j], LM, 64);
    float mr = sr[j], mi = si[j];
    sr[j] = gar*mr - gai*mi + gbr*pr - gbi*pi;
    si[j] = gar*mi + gai*mr + gbr*pi + gbi*pr;
  }
}

template<int W>
__device__ __forceinline__ void gen_wire(float (&sr)[16], float (&si)[16], int lane,
                                         const float* g)
{
  float g00r=g[0],g00i=g[1],g01r=g[2],g01i=g[3],g10r=g[4],g10i=g[5],g11r=g[6],g11i=g[7];
  if constexpr (W < 6) gen_cross<(1<<(5-W))>(sr,si,lane,g00r,g00i,g01r,g01i,g10r,g10i,g11r,g11i);
  else                 gen_local<(1<<(9-W))>(sr,si,g00r,g00i,g01r,g01i,g10r,g10i,g11r,g11i);
}

// Hadamard
template<int M>
__device__ __forceinline__ void h_local(float (&sr)[16], float (&si)[16])
{
#pragma unroll
  for (int j=0;j<16;++j) if (!(j&M)) {
    const int j1=j|M;
    float ar=sr[j],ai=si[j],br=sr[j1],bi=si[j1];
    sr[j]=R0*(ar+br);  si[j]=R0*(ai+bi);
    sr[j1]=R0*(ar-br); si[j1]=R0*(ai-bi);
  }
}
template<int LM>
__device__ __forceinline__ void h_cross(float (&sr)[16], float (&si)[16], int lane)
{
  const float sg = (lane & LM) ? -1.f : 1.f;
#pragma unroll
  for (int j=0;j<16;++j) {
    float pr=__shfl_xor(sr[j],LM,64), pi=__shfl_xor(si[j],LM,64);
    sr[j] = R0*fmaf(sg, sr[j], pr);
    si[j] = R0*fmaf(sg, si[j], pi);
  }
}
template<int W>
__device__ __forceinline__ void h_wire(float (&sr)[16], float (&si)[16], int lane)
{
  if constexpr (W < 6) h_cross<(1<<(5-W))>(sr,si,lane);
  else                 h_local<(1<<(9-W))>(sr,si);
}

// SX*H = r * [[1, i],[1, -i]]
template<int W>
__device__ __forceinline__ void sxh_wire(float (&sr)[16], float (&si)[16], int lane)
{
  if constexpr (W < 6) gen_cross<(1<<(5-W))>(sr,si,lane, R0,0.f, 0.f,R0, R0,0.f, 0.f,-R0);
  else                 gen_local<(1<<(9-W))>(sr,si,      R0,0.f, 0.f,R0, R0,0.f, 0.f,-R0);
}

// ---------------- CNOT ring -------------------------------------------------

// control lane bit0 (wire5), target local bit3 (wire6)
__device__ __forceinline__ void cnot_lane_local8(float (&sr)[16], float (&si)[16], int lane)
{
  const bool c = (lane & 1) != 0;
#pragma unroll
  for (int j=0;j<8;++j) {
    const int j1=j|8;
    float ar=sr[j], br=sr[j1];
    sr[j]=c?br:ar; sr[j1]=c?ar:br;
    float ai=si[j], bi=si[j1];
    si[j]=c?bi:ai; si[j1]=c?ai:bi;
  }
}
// both local: compile-time register swap (free after renaming)
template<int CM,int TM>
__device__ __forceinline__ void cnot_local(float (&sr)[16], float (&si)[16])
{
#pragma unroll
  for (int j=0;j<16;++j) if ((j&CM) && !(j&TM)) {
    const int j1=j|TM;
    float t=sr[j]; sr[j]=sr[j1]; sr[j1]=t;
    t=si[j]; si[j]=si[j1]; si[j1]=t;
  }
}
// control local bit0 (wire9), target lane bit5 (wire0)
__device__ __forceinline__ void cnot_local_lane(float (&sr)[16], float (&si)[16])
{
#pragma unroll
  for (int j=1;j<16;j+=2) {
    sr[j]=__shfl_xor(sr[j],32,64);
    si[j]=__shfl_xor(si[j],32,64);
  }
}

__device__ __forceinline__ void cnot_ring(float (&sr)[16], float (&si)[16], int lane)
{
  // CNOT(0,1)..(4,5): composed lane permutation, one bpermute round.
  const int addr = (lane ^ (lane >> 1)) << 2;
#pragma unroll
  for (int j=0;j<16;++j) {
    sr[j] = __int_as_float(__builtin_amdgcn_ds_bpermute(addr, __float_as_int(sr[j])));
    si[j] = __int_as_float(__builtin_amdgcn_ds_bpermute(addr, __float_as_int(si[j])));
  }
  cnot_lane_local8(sr,si,lane);  // (5,6)
  cnot_local<8,4>(sr,si);        // (6,7)
  cnot_local<4,2>(sr,si);        // (7,8)
  cnot_local<2,1>(sr,si);        // (8,9)
  cnot_local_lane(sr,si);        // (9,0)
}

// ---------------- measurement ----------------------------------------------
__device__ __forceinline__ void measure_store(const float (&sr)[16], const float (&si)[16],
                                              int lane, float* dst, float* dst2)
{
  float p[16];
#pragma unroll
  for (int j=0;j<16;++j) p[j] = fmaf(sr[j],sr[j], si[j]*si[j]);

  // j-tree: signed sums over local bits (wires 6..9) + total P
  float a[8]; float q9 = 0.f;
#pragma unroll
  for (int m=0;m<8;++m){ a[m] = p[2*m] + p[2*m+1]; q9 += p[2*m] - p[2*m+1]; }
  float bb[4]; float q8 = 0.f;
#pragma unroll
  for (int m=0;m<4;++m){ bb[m] = a[2*m] + a[2*m+1]; q8 += a[2*m] - a[2*m+1]; }
  float c0 = bb[0]+bb[1], c1 = bb[2]+bb[3];
  float q7 = (bb[0]-bb[1]) + (bb[2]-bb[3]);
  float q6 = c0 - c1;
  float P  = c0 + c1;

  // Walsh-Hadamard over lanes: lane l ends with sum_x P(x)(-1)^{popcount(l&x)}
  float v = P;
#pragma unroll
  for (int st=0; st<6; ++st) {
    const int m = 1<<st;
    float partner = __shfl_xor(v, m, 64);
    v = (lane & m) ? (partner - v) : (partner + v);
  }

#pragma unroll
  for (int m=1;m<64;m<<=1) {
    q6 += __shfl_xor(q6,m,64); q7 += __shfl_xor(q7,m,64);
    q8 += __shfl_xor(q8,m,64); q9 += __shfl_xor(q9,m,64);
  }

  if (lane==32){ dst[0]=v; if(dst2) dst2[0]=v; }
  if (lane==16){ dst[1]=v; if(dst2) dst2[1]=v; }
  if (lane== 8){ dst[2]=v; if(dst2) dst2[2]=v; }
  if (lane== 4){ dst[3]=v; if(dst2) dst2[3]=v; }
  if (lane== 2){ dst[4]=v; if(dst2) dst2[4]=v; }
  if (lane== 1){ dst[5]=v; if(dst2) dst2[5]=v; }
  if (lane== 0){
    dst[6]=q6; dst[7]=q7; dst[8]=q8; dst[9]=q9;
    if (dst2){ dst2[6]=q6; dst2[7]=q7; dst2[8]=q8; dst2[9]=q9; }
  }
}

// ---------------- kernels --------------------------------------------------

__global__ __launch_bounds__(320) void k_xq(const float* __restrict__ x,
                     const float* __restrict__ w, const float* __restrict__ b,
                     float* __restrict__ xq, float* __restrict__ ps1, float* __restrict__ ps2)
{
  __shared__ float wlds[40*41];
  __shared__ float xlds[320];
  __shared__ float accs[320];
  const int t = threadIdx.x;
  const int sl = t/40, f = t - sl*40;
  const int s0 = blockIdx.x*8;
#pragma unroll
  for (int i=0;i<5;++i) {
    int idx = t + i*320;
    int ff = idx/40, kk = idx - ff*40;
    wlds[ff*41+kk] = w[idx];
  }
  xlds[t] = x[s0*40 + t];
  __syncthreads();
  float acc = b[f];
#pragma unroll
  for (int k=0;k<40;++k) acc = fmaf(xlds[sl*40+k], wlds[f*41+k], acc);
  xq[s0*40 + t] = acc;
  accs[t] = acc;
  __syncthreads();
  if (t < 40) {
    float s1=0.f, s2=0.f;
#pragma unroll
    for (int m=0;m<8;++m){ float vv=accs[m*40+t]; s1+=vv; s2=fmaf(vv,vv,s2); }
    ps1[t*1024 + blockIdx.x] = s1;
    ps2[t*1024 + blockIdx.x] = s2;
  }
}

__global__ void k_bn(const float* __restrict__ ps1, const float* __restrict__ ps2,
                     const float* __restrict__ gamma, const float* __restrict__ beta,
                     float* __restrict__ bn_a, float* __restrict__ bn_c)
{
  const int f = blockIdx.x, t = threadIdx.x;
  float s1=0.f, s2=0.f;
#pragma unroll
  for (int i=0;i<4;++i){ s1 += ps1[f*1024 + t + i*256]; s2 += ps2[f*1024 + t + i*256]; }
  __shared__ float a1[256], a2[256];
  a1[t]=s1; a2[t]=s2; __syncthreads();
  for (int off=128; off; off>>=1){
    if (t<off){ a1[t]+=a1[t+off]; a2[t]+=a2[t+off]; }
    __syncthreads();
  }
  if (t==0) {
    float mu = a1[0]*(1.f/8192.f);
    float var = a2[0]*(1.f/8192.f) - mu*mu;
    float a = gamma[f]*rsqrtf(var + 1e-5f);
    bn_a[f]=a; bn_c[f]=beta[f]-mu*a;
  }
}

__global__ void k_consts(const float* __restrict__ rz1, const float* __restrict__ ry1,
                         const float* __restrict__ rz2, float* __restrict__ gates)
{
  int t = threadIdx.x;
  if (t < 40) {
    float g = rz1[t], a = ry1[t], b = rz2[t];
    float ca, sa, cp, sp, cm, sm;
    sincosf(0.5f*a, &sa, &ca);
    sincosf(0.5f*(b+g), &sp, &cp);
    sincosf(0.5f*(b-g), &sm, &cm);
    float* G = gates + t*8;
    G[0]= ca*cp; G[1]=-ca*sp;
    G[2]=-sa*cm; G[3]= sa*sm;
    G[4]= sa*cm; G[5]= sa*sm;
    G[6]= ca*cp; G[7]= ca*sp;
  }
}

#define GEN10(PTR) \
  gen_wire<0>(sr,si,lane,(PTR)+0);  gen_wire<1>(sr,si,lane,(PTR)+8);  \
  gen_wire<2>(sr,si,lane,(PTR)+16); gen_wire<3>(sr,si,lane,(PTR)+24); \
  gen_wire<4>(sr,si,lane,(PTR)+32); gen_wire<5>(sr,si,lane,(PTR)+40); \
  gen_wire<6>(sr,si,lane,(PTR)+48); gen_wire<7>(sr,si,lane,(PTR)+56); \
  gen_wire<8>(sr,si,lane,(PTR)+64); gen_wire<9>(sr,si,lane,(PTR)+72);

// Plain launch bounds — see header comment; min-waves arg causes spill cascade.
__global__ __launch_bounds__(256) void k_qnn(const float* __restrict__ xq,
    const float* __restrict__ bn_a, const float* __restrict__ bn_c,
    const float* __restrict__ gates, float* __restrict__ x1)
{
  const int lane = threadIdx.x & 63;
  const int wv   = threadIdx.x >> 6;
  const int s    = blockIdx.x*4 + wv;

  __shared__ float Ebuf[4][10][8];
  __shared__ float Fbuf[4][3][10][8];

  // ---- per-sample fused encoder matrix per wire: Rx(f3) Rz(f2) Ry(f1) Rx(f0)
  if (lane < 10) {
    const int i = lane;
    const int f = 4*i;
    float h0 = 0.5f * fmaf(xq[s*40+f+0], bn_a[f+0], bn_c[f+0]);
    float h1 = 0.5f * fmaf(xq[s*40+f+1], bn_a[f+1], bn_c[f+1]);
    float h2 = 0.5f * fmaf(xq[s*40+f+2], bn_a[f+2], bn_c[f+2]);
    float h3 = 0.5f * fmaf(xq[s*40+f+3], bn_a[f+3], bn_c[f+3]);
    float c0,s0,c1,s1,c2,s2,c3,s3;
    sincosf(h0,&s0,&c0); sincosf(h1,&s1,&c1);
    sincosf(h2,&s2,&c2); sincosf(h3,&s3,&c3);
    float A00r=c1*c0, A00i= s1*s0;
    float A01r=-s1*c0, A01i=-c1*s0;
    float A10r= s1*c0, A10i=-c1*s0;
    float A11r= c1*c0, A11i=-s1*s0;
    float B00r = A00r*c2 + A00i*s2, B00i = A00i*c2 - A00r*s2;
    float B01r = A01r*c2 + A01i*s2, B01i = A01i*c2 - A01r*s2;
    float B10r = A10r*c2 - A10i*s2, B10i = A10i*c2 + A10r*s2;
    float B11r = A11r*c2 - A11i*s2, B11i = A11i*c2 + A11r*s2;
    float* e = &Ebuf[wv][i][0];
    e[0] = c3*B00r + s3*B10i;  e[1] = c3*B00i - s3*B10r;
    e[2] = c3*B01r + s3*B11i;  e[3] = c3*B01i - s3*B11r;
    e[4] = c3*B10r + s3*B00i;  e[5] = c3*B10i - s3*B00r;
    e[6] = c3*B11r + s3*B01i;  e[7] = c3*B11i - s3*B01r;
  }
  __syncthreads();

  // ---- fused F_k = U_{k+1} * E  (30 lanes, one 2x2 complex product each)
  if (lane < 30) {
    const int k = lane/10, i = lane - k*10;
    const float* U = gates + (k+1)*80 + i*8;
    const float* E = &Ebuf[wv][i][0];
    float u00r=U[0],u00i=U[1],u01r=U[2],u01i=U[3],u10r=U[4],u10i=U[5],u11r=U[6],u11i=U[7];
    float e00r=E[0],e00i=E[1],e01r=E[2],e01i=E[3],e10r=E[4],e10i=E[5],e11r=E[6],e11i=E[7];
    float* F = &Fbuf[wv][k][i][0];
    F[0] = u00r*e00r - u00i*e00i + u01r*e10r - u01i*e10i;
    F[1] = u00r*e00i + u00i*e00r + u01r*e10i + u01i*e10r;
    F[2] = u00r*e01r - u00i*e01i + u01r*e11r - u01i*e11i;
    F[3] = u00r*e01i + u00i*e01r + u01r*e11i + u01i*e11r;
    F[4] = u10r*e00r - u10i*e00i + u11r*e10r - u11i*e10i;
    F[5] = u10r*e00i + u10i*e00r + u11r*e10i + u11i*e10r;
    F[6] = u10r*e01r - u10i*e01i + u11r*e11r - u11i*e11i;
    F[7] = u10r*e01i + u10i*e01r + u11r*e11i + u11i*e11r;
  }
  __syncthreads();

  // ---- init: state = U0 |0..0>  (product state, column 0 per wire)
  float sr[16], si[16];
  {
    float cr = 1.f, ci = 0.f;
#pragma unroll
    for (int w=0; w<6; ++w) {
      const float g0r = gates[w*8+0], g0i = gates[w*8+1];
      const float g1r = gates[w*8+4], g1i = gates[w*8+5];
      const bool bset = (lane >> (5-w)) & 1;
      const float ar = bset ? g1r : g0r, ai = bset ? g1i : g0i;
      const float tr = cr*ar - ci*ai, ti = cr*ai + ci*ar;
      cr = tr; ci = ti;
    }
    float p67r[4], p67i[4], p89r[4], p89i[4];
#pragma unroll
    for (int b6=0;b6<2;++b6)
#pragma unroll
      for (int b7=0;b7<2;++b7) {
        const float x6r = gates[6*8 + 4*b6], x6i = gates[6*8 + 4*b6 + 1];
        const float x7r = gates[7*8 + 4*b7], x7i = gates[7*8 + 4*b7 + 1];
        p67r[b6*2+b7] = x6r*x7r - x6i*x7i;
        p67i[b6*2+b7] = x6r*x7i + x6i*x7r;
      }
#pragma unroll
    for (int b8=0;b8<2;++b8)
#pragma unroll
      for (int b9=0;b9<2;++b9) {
        const float x8r = gates[8*8 + 4*b8], x8i = gates[8*8 + 4*b8 + 1];
        const float x9r = gates[9*8 + 4*b9], x9i = gates[9*8 + 4*b9 + 1];
        p89r[b8*2+b9] = x8r*x9r - x8i*x9i;
        p89i[b8*2+b9] = x8r*x9i + x8i*x9r;
      }
#pragma unroll
    for (int m=0;m<4;++m) {
      const float tr = p67r[m]*cr - p67i[m]*ci;
      const float ti = p67r[m]*ci + p67i[m]*cr;
      p67r[m]=tr; p67i[m]=ti;
    }
#pragma unroll
    for (int j=0;j<16;++j) {
      const int hi = j>>2, lo = j&3;
      sr[j] = p67r[hi]*p89r[lo] - p67i[hi]*p89i[lo];
      si[j] = p67r[hi]*p89i[lo] + p67i[hi]*p89r[lo];
    }
  }

  // ---- main circuit: 4 rings interleaved with 3 fused layers
  cnot_ring(sr,si,lane);
  { const float* F = &Fbuf[wv][0][0][0]; GEN10(F) }
  cnot_ring(sr,si,lane);
  { const float* F = &Fbuf[wv][1][0][0]; GEN10(F) }
  cnot_ring(sr,si,lane);
  { const float* F = &Fbuf[wv][2][0][0]; GEN10(F) }
  cnot_ring(sr,si,lane);

  float* dst = x1 + s*40;
  measure_store(sr,si,lane,dst,nullptr);

  h_wire<0>(sr,si,lane); h_wire<1>(sr,si,lane); h_wire<2>(sr,si,lane);
  h_wire<3>(sr,si,lane); h_wire<4>(sr,si,lane); h_wire<5>(sr,si,lane);
  h_wire<6>(sr,si,lane); h_wire<7>(sr,si,lane); h_wire<8>(sr,si,lane);
  h_wire<9>(sr,si,lane);
  measure_store(sr,si,lane,dst+10,nullptr);

  sxh_wire<0>(sr,si,lane); sxh_wire<1>(sr,si,lane); sxh_wire<2>(sr,si,lane);
  sxh_wire<3>(sr,si,lane); sxh_wire<4>(sr,si,lane); sxh_wire<5>(sr,si,lane);
  sxh_wire<6>(sr,si,lane); sxh_wire<7>(sr,si,lane); sxh_wire<8>(sr,si,lane);
  sxh_wire<9>(sr,si,lane);
  measure_store(sr,si,lane,dst+20,dst+30);
}

__global__ void k_epi(const float* __restrict__ x, const float* __restrict__ x1,
                      const float* __restrict__ clin_w, const float* __restrict__ clin_b,
                      const float* __restrict__ lin_w, const float* __restrict__ lin_b,
                      float* __restrict__ out)
{
  const int t = threadIdx.x;
  const int sl = t/40, f = t - sl*40;
  const int s = blockIdx.x*8 + sl;
  __shared__ float x2s[8][40];
  float acc = clin_b[f];
#pragma unroll
  for (int k=0;k<40;++k) acc = fmaf(x[s*40+k], clin_w[f*40+k], acc);
  x2s[sl][f] = fmaxf(acc, 0.f);
  __syncthreads();
  float o = lin_b[f];
#pragma unroll
  for (int j=0;j<40;++j) o = fmaf(x1[s*40+j], lin_w[f*80+j], o);
#pragma unroll
  for (int j=0;j<40;++j) o = fmaf(x2s[sl][j], lin_w[f*80+40+j], o);
  out[s*40+f] = o;
}

// ---------------- launch ---------------------------------------------------
extern "C" void kernel_launch(void* const* d_in, const int* in_sizes, int n_in,
                              void* d_out, int out_size, void* d_ws, size_t ws_size,
                              hipStream_t stream)
{
  const float* x      = (const float*)d_in[0];
  const float* qlin_w = (const float*)d_in[1];
  const float* qlin_b = (const float*)d_in[2];
  const float* bn_g   = (const float*)d_in[3];
  const float* bn_b   = (const float*)d_in[4];
  const float* clin_w = (const float*)d_in[5];
  const float* clin_b = (const float*)d_in[6];
  const float* lin_w  = (const float*)d_in[7];
  const float* lin_b  = (const float*)d_in[8];
  const float* rz1    = (const float*)d_in[9];
  const float* ry1    = (const float*)d_in[10];
  const float* rz2    = (const float*)d_in[11];

  float* ws    = (float*)d_ws;
  float* xq    = ws + WS_XQ;
  float* x1    = ws + WS_X1;
  float* ps1   = ws + WS_PS1;
  float* ps2   = ws + WS_PS2;
  float* bn_a  = ws + WS_BNA;
  float* bn_c  = ws + WS_BNC;
  float* gates = ws + WS_GATES;
  float* out   = (float*)d_out;

  hipLaunchKernelGGL(k_consts, dim3(1),    dim3(64),  0, stream, rz1, ry1, rz2, gates);
  hipLaunchKernelGGL(k_xq,     dim3(1024), dim3(320), 0, stream, x, qlin_w, qlin_b, xq, ps1, ps2);
  hipLaunchKernelGGL(k_bn,     dim3(40),   dim3(256), 0, stream, ps1, ps2, bn_g, bn_b, bn_a, bn_c);
  hipLaunchKernelGGL(k_qnn,    dim3(2048), dim3(256), 0, stream, xq, bn_a, bn_c, gates, x1);
  hipLaunchKernelGGL(k_epi,    dim3(1024), dim3(320), 0, stream, x, x1, clin_w, clin_b, lin_w, lin_b, out);
}

// Round 5
// 228.854 us; speedup vs baseline: 4.0558x; 1.0802x over previous
//
#include <hip/hip_runtime.h>
#include <math.h>

// ---------------------------------------------------------------------------
// QINRLayer: Linear+BN -> 10-qubit QNN (statevector sim) -> classical branch
// One wave per sample; 1024 complex amps in registers (16/lane).
// k = lane*16 + j ; wire w (0=MSB) <-> lane bit (5-w) for w<6, j bit (9-w) else.
//
// Circuit algebra (all exact):
//   U0|0..0> is a product state -> direct init, no gate pass.
//   encode(E) then param layer U_{k+1} fuse into F_k = U_{k+1} * E.
//   CNOTs (0,1)..(4,5) compose into lane perm  src = lane ^ (lane>>1).
//   outs[1] = <X_w>:  H then Z-measure == 2 Re(a conj b) per pair.
//   outs[2] = -<Y_w>: (H;SX) after the H block == SX on psi0 (H*H=I);
//             Z after SX == -2 Im(a conj b) per pair.
//   rz3 diagonal -> outs[3] == outs[2].
//   => NO post-circuit gate passes at all; everything from psi0 pair products.
//
// HARD-WON: do NOT set a min-waves-per-EU in __launch_bounds__ on k_qnn.
//   R1: __launch_bounds__(256)   -> 88 VGPR, no spill, VALU 66%
//   R2: __launch_bounds__(256,6) -> 40 VGPR, state spilled, 3.3 GB HBM
//   R3: __launch_bounds__(256,5) -> 48 VGPR, state spilled, 1.7 GB HBM
//   R4: __launch_bounds__(256)   -> 100 VGPR, no spill, 176 us
// ---------------------------------------------------------------------------

#define R0 0.70710678118654752f

// ws layout (floats)
#define WS_XQ    0         // 8192*40
#define WS_X1    327680    // 8192*40   (ps1/ps2 alias this region, consumed first)
#define WS_PS1   327680    // 40*1024
#define WS_PS2   368640    // 40*1024
#define WS_BNA   655360    // 40
#define WS_BNC   655400    // 40
#define WS_GATES 655440    // 40 gates * 8 floats (fused rz2*ry1*rz1 per block,wire)

// ---------------- gate primitives (state in registers) ---------------------

template<int M>
__device__ __forceinline__ void gen_local(float (&sr)[16], float (&si)[16],
    float g00r,float g00i,float g01r,float g01i,
    float g10r,float g10i,float g11r,float g11i)
{
#pragma unroll
  for (int j=0;j<16;++j) if (!(j&M)) {
    const int j1=j|M;
    float ar=sr[j],ai=si[j],br=sr[j1],bi=si[j1];
    sr[j]  = g00r*ar - g00i*ai + g01r*br - g01i*bi;
    si[j]  = g00r*ai + g00i*ar + g01r*bi + g01i*br;
    sr[j1] = g10r*ar - g10i*ai + g11r*br - g11i*bi;
    si[j1] = g10r*ai + g10i*ar + g11r*bi + g11i*br;
  }
}

template<int LM>
__device__ __forceinline__ void gen_cross(float (&sr)[16], float (&si)[16], int lane,
    float g00r,float g00i,float g01r,float g01i,
    float g10r,float g10i,float g11r,float g11i)
{
  const bool hi = (lane & LM) != 0;
  const float gar = hi ? g11r : g00r;
  const float gai = hi ? g11i : g00i;
  const float gbr = hi ? g10r : g01r;
  const float gbi = hi ? g10i : g01i;
#pragma unroll
  for (int j=0;j<16;++j) {
    float pr = __shfl_xor(sr[j], LM, 64);
    float pi = __shfl_xor(si[j], LM, 64);
    float mr = sr[j], mi = si[j];
    sr[j] = gar*mr - gai*mi + gbr*pr - gbi*pi;
    si[j] = gar*mi + gai*mr + gbr*pi + gbi*pr;
  }
}

template<int W>
__device__ __forceinline__ void gen_wire(float (&sr)[16], float (&si)[16], int lane,
                                         const float* g)
{
  float g00r=g[0],g00i=g[1],g01r=g[2],g01i=g[3],g10r=g[4],g10i=g[5],g11r=g[6],g11i=g[7];
  if constexpr (W < 6) gen_cross<(1<<(5-W))>(sr,si,lane,g00r,g00i,g01r,g01i,g10r,g10i,g11r,g11i);
  else                 gen_local<(1<<(9-W))>(sr,si,g00r,g00i,g01r,g01i,g10r,g10i,g11r,g11i);
}

// ---------------- CNOT ring -------------------------------------------------

// control lane bit0 (wire5), target local bit3 (wire6)
__device__ __forceinline__ void cnot_lane_local8(float (&sr)[16], float (&si)[16], int lane)
{
  const bool c = (lane & 1) != 0;
#pragma unroll
  for (int j=0;j<8;++j) {
    const int j1=j|8;
    float ar=sr[j], br=sr[j1];
    sr[j]=c?br:ar; sr[j1]=c?ar:br;
    float ai=si[j], bi=si[j1];
    si[j]=c?bi:ai; si[j1]=c?ai:bi;
  }
}
// both local: compile-time register swap (free after renaming)
template<int CM,int TM>
__device__ __forceinline__ void cnot_local(float (&sr)[16], float (&si)[16])
{
#pragma unroll
  for (int j=0;j<16;++j) if ((j&CM) && !(j&TM)) {
    const int j1=j|TM;
    float t=sr[j]; sr[j]=sr[j1]; sr[j1]=t;
    t=si[j]; si[j]=si[j1]; si[j1]=t;
  }
}
// control local bit0 (wire9), target lane bit5 (wire0)
__device__ __forceinline__ void cnot_local_lane(float (&sr)[16], float (&si)[16])
{
#pragma unroll
  for (int j=1;j<16;j+=2) {
    sr[j]=__shfl_xor(sr[j],32,64);
    si[j]=__shfl_xor(si[j],32,64);
  }
}

__device__ __forceinline__ void cnot_ring(float (&sr)[16], float (&si)[16], int lane)
{
  // CNOT(0,1)..(4,5): composed lane permutation, one bpermute round.
  const int addr = (lane ^ (lane >> 1)) << 2;
#pragma unroll
  for (int j=0;j<16;++j) {
    sr[j] = __int_as_float(__builtin_amdgcn_ds_bpermute(addr, __float_as_int(sr[j])));
    si[j] = __int_as_float(__builtin_amdgcn_ds_bpermute(addr, __float_as_int(si[j])));
  }
  cnot_lane_local8(sr,si,lane);  // (5,6)
  cnot_local<8,4>(sr,si);        // (6,7)
  cnot_local<4,2>(sr,si);        // (7,8)
  cnot_local<2,1>(sr,si);        // (8,9)
  cnot_local_lane(sr,si);        // (9,0)
}

// ---------------- measurement ----------------------------------------------

__device__ __forceinline__ float wave_sum(float x)
{
#pragma unroll
  for (int m=1;m<64;m<<=1) x += __shfl_xor(x,m,64);
  return x;
}

// outs[0]: <Z_w> from probabilities of psi0.
__device__ __forceinline__ void measure_z(const float (&sr)[16], const float (&si)[16],
                                          int lane, float* dst)
{
  float p[16];
#pragma unroll
  for (int j=0;j<16;++j) p[j] = fmaf(sr[j],sr[j], si[j]*si[j]);

  // j-tree: signed sums over local bits (wires 6..9) + total P
  float a[8]; float q9 = 0.f;
#pragma unroll
  for (int m=0;m<8;++m){ a[m] = p[2*m] + p[2*m+1]; q9 += p[2*m] - p[2*m+1]; }
  float bb[4]; float q8 = 0.f;
#pragma unroll
  for (int m=0;m<4;++m){ bb[m] = a[2*m] + a[2*m+1]; q8 += a[2*m] - a[2*m+1]; }
  float c0 = bb[0]+bb[1], c1 = bb[2]+bb[3];
  float q7 = (bb[0]-bb[1]) + (bb[2]-bb[3]);
  float q6 = c0 - c1;
  float P  = c0 + c1;

  // Walsh-Hadamard over lanes: lane l ends with sum_x P(x)(-1)^{popcount(l&x)}
  float v = P;
#pragma unroll
  for (int st=0; st<6; ++st) {
    const int m = 1<<st;
    float partner = __shfl_xor(v, m, 64);
    v = (lane & m) ? (partner - v) : (partner + v);
  }

#pragma unroll
  for (int m=1;m<64;m<<=1) {
    q6 += __shfl_xor(q6,m,64); q7 += __shfl_xor(q7,m,64);
    q8 += __shfl_xor(q8,m,64); q9 += __shfl_xor(q9,m,64);
  }

  if (lane==32) dst[0]=v;
  if (lane==16) dst[1]=v;
  if (lane== 8) dst[2]=v;
  if (lane== 4) dst[3]=v;
  if (lane== 2) dst[4]=v;
  if (lane== 1) dst[5]=v;
  if (lane== 0){ dst[6]=q6; dst[7]=q7; dst[8]=q8; dst[9]=q9; }
}

// outs[1][w]=<X_w>, outs[2][w]=outs[3][w]=-<Y_w>, from psi0 pair products.
// cross wire (lane mask LM): u_k = sum_j Re(loc conj part), v_k = Im(...)
//   X = sum_k u_k ;  out2 = sum_k ((lane&LM)? v_k : -v_k)
template<int LM>
__device__ __forceinline__ void xy_cross(const float (&sr)[16], const float (&si)[16],
                                         int lane, float* dst, int w)
{
  float u=0.f, v=0.f;
#pragma unroll
  for (int j=0;j<16;++j) {
    float pr = __shfl_xor(sr[j], LM, 64);
    float pi = __shfl_xor(si[j], LM, 64);
    u = fmaf(sr[j],pr,u); u = fmaf(si[j],pi,u);
    v = fmaf(si[j],pr,v); v = fmaf(-sr[j],pi,v);
  }
  v = (lane & LM) ? v : -v;
  u = wave_sum(u);
  v = wave_sum(v);
  if (lane==0){ dst[10+w]=u; dst[20+w]=v; dst[30+w]=v; }
}

// local wire (j mask M): pairs counted once -> X = 2*sum, out2 = -2*sum(Im)
template<int M>
__device__ __forceinline__ void xy_local(const float (&sr)[16], const float (&si)[16],
                                         int lane, float* dst, int w)
{
  float u=0.f, v=0.f;
#pragma unroll
  for (int j=0;j<16;++j) if (!(j&M)) {
    const int j1=j|M;
    u = fmaf(sr[j],sr[j1],u); u = fmaf(si[j],si[j1],u);
    v = fmaf(si[j],sr[j1],v); v = fmaf(-sr[j],si[j1],v);
  }
  u = wave_sum(u);
  v = wave_sum(v);
  if (lane==0){ dst[10+w]=2.f*u; float y=-2.f*v; dst[20+w]=y; dst[30+w]=y; }
}

// ---------------- kernels --------------------------------------------------

__global__ __launch_bounds__(320) void k_xq(const float* __restrict__ x,
                     const float* __restrict__ w, const float* __restrict__ b,
                     float* __restrict__ xq, float* __restrict__ ps1, float* __restrict__ ps2)
{
  __shared__ float wlds[40*41];
  __shared__ float xlds[320];
  __shared__ float accs[320];
  const int t = threadIdx.x;
  const int sl = t/40, f = t - sl*40;
  const int s0 = blockIdx.x*8;
#pragma unroll
  for (int i=0;i<5;++i) {
    int idx = t + i*320;
    int ff = idx/40, kk = idx - ff*40;
    wlds[ff*41+kk] = w[idx];
  }
  xlds[t] = x[s0*40 + t];
  __syncthreads();
  float acc = b[f];
#pragma unroll
  for (int k=0;k<40;++k) acc = fmaf(xlds[sl*40+k], wlds[f*41+k], acc);
  xq[s0*40 + t] = acc;
  accs[t] = acc;
  __syncthreads();
  if (t < 40) {
    float s1=0.f, s2=0.f;
#pragma unroll
    for (int m=0;m<8;++m){ float vv=accs[m*40+t]; s1+=vv; s2=fmaf(vv,vv,s2); }
    ps1[t*1024 + blockIdx.x] = s1;
    ps2[t*1024 + blockIdx.x] = s2;
  }
}

// grid 41: blocks 0..39 = BN reduce for one feature; block 40 = gate consts
__global__ void k_bn(const float* __restrict__ ps1, const float* __restrict__ ps2,
                     const float* __restrict__ gamma, const float* __restrict__ beta,
                     const float* __restrict__ rz1, const float* __restrict__ ry1,
                     const float* __restrict__ rz2,
                     float* __restrict__ bn_a, float* __restrict__ bn_c,
                     float* __restrict__ gates)
{
  const int f = blockIdx.x, t = threadIdx.x;
  if (f == 40) {
    if (t < 40) {
      float g = rz1[t], a = ry1[t], b = rz2[t];
      float ca, sa, cp, sp, cm, sm;
      sincosf(0.5f*a, &sa, &ca);
      sincosf(0.5f*(b+g), &sp, &cp);
      sincosf(0.5f*(b-g), &sm, &cm);
      float* G = gates + t*8;
      G[0]= ca*cp; G[1]=-ca*sp;
      G[2]=-sa*cm; G[3]= sa*sm;
      G[4]= sa*cm; G[5]= sa*sm;
      G[6]= ca*cp; G[7]= ca*sp;
    }
    return;
  }
  float s1=0.f, s2=0.f;
#pragma unroll
  for (int i=0;i<4;++i){ s1 += ps1[f*1024 + t + i*256]; s2 += ps2[f*1024 + t + i*256]; }
  __shared__ float a1[256], a2[256];
  a1[t]=s1; a2[t]=s2; __syncthreads();
  for (int off=128; off; off>>=1){
    if (t<off){ a1[t]+=a1[t+off]; a2[t]+=a2[t+off]; }
    __syncthreads();
  }
  if (t==0) {
    float mu = a1[0]*(1.f/8192.f);
    float var = a2[0]*(1.f/8192.f) - mu*mu;
    float a = gamma[f]*rsqrtf(var + 1e-5f);
    bn_a[f]=a; bn_c[f]=beta[f]-mu*a;
  }
}

#define GEN10(PTR) \
  gen_wire<0>(sr,si,lane,(PTR)+0);  gen_wire<1>(sr,si,lane,(PTR)+8);  \
  gen_wire<2>(sr,si,lane,(PTR)+16); gen_wire<3>(sr,si,lane,(PTR)+24); \
  gen_wire<4>(sr,si,lane,(PTR)+32); gen_wire<5>(sr,si,lane,(PTR)+40); \
  gen_wire<6>(sr,si,lane,(PTR)+48); gen_wire<7>(sr,si,lane,(PTR)+56); \
  gen_wire<8>(sr,si,lane,(PTR)+64); gen_wire<9>(sr,si,lane,(PTR)+72);

// Plain launch bounds — see header comment; min-waves arg causes spill cascade.
__global__ __launch_bounds__(256) void k_qnn(const float* __restrict__ xq,
    const float* __restrict__ bn_a, const float* __restrict__ bn_c,
    const float* __restrict__ gates, float* __restrict__ x1)
{
  const int lane = threadIdx.x & 63;
  const int wv   = threadIdx.x >> 6;
  const int s    = blockIdx.x*4 + wv;

  __shared__ float Ebuf[4][10][8];
  __shared__ float Fbuf[4][3][10][8];

  // ---- per-sample fused encoder matrix per wire: Rx(f3) Rz(f2) Ry(f1) Rx(f0)
  if (lane < 10) {
    const int i = lane;
    const int f = 4*i;
    float h0 = 0.5f * fmaf(xq[s*40+f+0], bn_a[f+0], bn_c[f+0]);
    float h1 = 0.5f * fmaf(xq[s*40+f+1], bn_a[f+1], bn_c[f+1]);
    float h2 = 0.5f * fmaf(xq[s*40+f+2], bn_a[f+2], bn_c[f+2]);
    float h3 = 0.5f * fmaf(xq[s*40+f+3], bn_a[f+3], bn_c[f+3]);
    float c0,s0,c1,s1,c2,s2,c3,s3;
    sincosf(h0,&s0,&c0); sincosf(h1,&s1,&c1);
    sincosf(h2,&s2,&c2); sincosf(h3,&s3,&c3);
    float A00r=c1*c0, A00i= s1*s0;
    float A01r=-s1*c0, A01i=-c1*s0;
    float A10r= s1*c0, A10i=-c1*s0;
    float A11r= c1*c0, A11i=-s1*s0;
    float B00r = A00r*c2 + A00i*s2, B00i = A00i*c2 - A00r*s2;
    float B01r = A01r*c2 + A01i*s2, B01i = A01i*c2 - A01r*s2;
    float B10r = A10r*c2 - A10i*s2, B10i = A10i*c2 + A10r*s2;
    float B11r = A11r*c2 - A11i*s2, B11i = A11i*c2 + A11r*s2;
    float* e = &Ebuf[wv][i][0];
    e[0] = c3*B00r + s3*B10i;  e[1] = c3*B00i - s3*B10r;
    e[2] = c3*B01r + s3*B11i;  e[3] = c3*B01i - s3*B11r;
    e[4] = c3*B10r + s3*B00i;  e[5] = c3*B10i - s3*B00r;
    e[6] = c3*B11r + s3*B01i;  e[7] = c3*B11i - s3*B01r;
  }
  __syncthreads();

  // ---- fused F_k = U_{k+1} * E  (30 lanes, one 2x2 complex product each)
  if (lane < 30) {
    const int k = lane/10, i = lane - k*10;
    const float* U = gates + (k+1)*80 + i*8;
    const float* E = &Ebuf[wv][i][0];
    float u00r=U[0],u00i=U[1],u01r=U[2],u01i=U[3],u10r=U[4],u10i=U[5],u11r=U[6],u11i=U[7];
    float e00r=E[0],e00i=E[1],e01r=E[2],e01i=E[3],e10r=E[4],e10i=E[5],e11r=E[6],e11i=E[7];
    float* F = &Fbuf[wv][k][i][0];
    F[0] = u00r*e00r - u00i*e00i + u01r*e10r - u01i*e10i;
    F[1] = u00r*e00i + u00i*e00r + u01r*e10i + u01i*e10r;
    F[2] = u00r*e01r - u00i*e01i + u01r*e11r - u01i*e11i;
    F[3] = u00r*e01i + u00i*e01r + u01r*e11i + u01i*e11r;
    F[4] = u10r*e00r - u10i*e00i + u11r*e10r - u11i*e10i;
    F[5] = u10r*e00i + u10i*e00r + u11r*e10i + u11i*e10r;
    F[6] = u10r*e01r - u10i*e01i + u11r*e11r - u11i*e11i;
    F[7] = u10r*e01i + u10i*e01r + u11r*e11i + u11i*e11r;
  }
  __syncthreads();

  // ---- init: state = U0 |0..0>  (product state, column 0 per wire)
  float sr[16], si[16];
  {
    float cr = 1.f, ci = 0.f;
#pragma unroll
    for (int w=0; w<6; ++w) {
      const float g0r = gates[w*8+0], g0i = gates[w*8+1];
      const float g1r = gates[w*8+4], g1i = gates[w*8+5];
      const bool bset = (lane >> (5-w)) & 1;
      const float ar = bset ? g1r : g0r, ai = bset ? g1i : g0i;
      const float tr = cr*ar - ci*ai, ti = cr*ai + ci*ar;
      cr = tr; ci = ti;
    }
    float p67r[4], p67i[4], p89r[4], p89i[4];
#pragma unroll
    for (int b6=0;b6<2;++b6)
#pragma unroll
      for (int b7=0;b7<2;++b7) {
        const float x6r = gates[6*8 + 4*b6], x6i = gates[6*8 + 4*b6 + 1];
        const float x7r = gates[7*8 + 4*b7], x7i = gates[7*8 + 4*b7 + 1];
        p67r[b6*2+b7] = x6r*x7r - x6i*x7i;
        p67i[b6*2+b7] = x6r*x7i + x6i*x7r;
      }
#pragma unroll
    for (int b8=0;b8<2;++b8)
#pragma unroll
      for (int b9=0;b9<2;++b9) {
        const float x8r = gates[8*8 + 4*b8], x8i = gates[8*8 + 4*b8 + 1];
        const float x9r = gates[9*8 + 4*b9], x9i = gates[9*8 + 4*b9 + 1];
        p89r[b8*2+b9] = x8r*x9r - x8i*x9i;
        p89i[b8*2+b9] = x8r*x9i + x8i*x9r;
      }
#pragma unroll
    for (int m=0;m<4;++m) {
      const float tr = p67r[m]*cr - p67i[m]*ci;
      const float ti = p67r[m]*ci + p67i[m]*cr;
      p67r[m]=tr; p67i[m]=ti;
    }
#pragma unroll
    for (int j=0;j<16;++j) {
      const int hi = j>>2, lo = j&3;
      sr[j] = p67r[hi]*p89r[lo] - p67i[hi]*p89i[lo];
      si[j] = p67r[hi]*p89i[lo] + p67i[hi]*p89r[lo];
    }
  }

  // ---- main circuit: 4 rings interleaved with 3 fused layers
  cnot_ring(sr,si,lane);
  { const float* F = &Fbuf[wv][0][0][0]; GEN10(F) }
  cnot_ring(sr,si,lane);
  { const float* F = &Fbuf[wv][1][0][0]; GEN10(F) }
  cnot_ring(sr,si,lane);
  { const float* F = &Fbuf[wv][2][0][0]; GEN10(F) }
  cnot_ring(sr,si,lane);

  // ---- all 4 outputs directly from psi0
  float* dst = x1 + s*40;
  measure_z(sr,si,lane,dst);
  xy_cross<32>(sr,si,lane,dst,0);
  xy_cross<16>(sr,si,lane,dst,1);
  xy_cross< 8>(sr,si,lane,dst,2);
  xy_cross< 4>(sr,si,lane,dst,3);
  xy_cross< 2>(sr,si,lane,dst,4);
  xy_cross< 1>(sr,si,lane,dst,5);
  xy_local< 8>(sr,si,lane,dst,6);
  xy_local< 4>(sr,si,lane,dst,7);
  xy_local< 2>(sr,si,lane,dst,8);
  xy_local< 1>(sr,si,lane,dst,9);
}

__global__ void k_epi(const float* __restrict__ x, const float* __restrict__ x1,
                      const float* __restrict__ clin_w, const float* __restrict__ clin_b,
                      const float* __restrict__ lin_w, const float* __restrict__ lin_b,
                      float* __restrict__ out)
{
  const int t = threadIdx.x;
  const int sl = t/40, f = t - sl*40;
  const int s = blockIdx.x*8 + sl;
  __shared__ float x2s[8][40];
  float acc = clin_b[f];
#pragma unroll
  for (int k=0;k<40;++k) acc = fmaf(x[s*40+k], clin_w[f*40+k], acc);
  x2s[sl][f] = fmaxf(acc, 0.f);
  __syncthreads();
  float o = lin_b[f];
#pragma unroll
  for (int j=0;j<40;++j) o = fmaf(x1[s*40+j], lin_w[f*80+j], o);
#pragma unroll
  for (int j=0;j<40;++j) o = fmaf(x2s[sl][j], lin_w[f*80+40+j], o);
  out[s*40+f] = o;
}

// ---------------- launch ---------------------------------------------------
extern "C" void kernel_launch(void* const* d_in, const int* in_sizes, int n_in,
                              void* d_out, int out_size, void* d_ws, size_t ws_size,
                              hipStream_t stream)
{
  const float* x      = (const float*)d_in[0];
  const float* qlin_w = (const float*)d_in[1];
  const float* qlin_b = (const float*)d_in[2];
  const float* bn_g   = (const float*)d_in[3];
  const float* bn_b   = (const float*)d_in[4];
  const float* clin_w = (const float*)d_in[5];
  const float* clin_b = (const float*)d_in[6];
  const float* lin_w  = (const float*)d_in[7];
  const float* lin_b  = (const float*)d_in[8];
  const float* rz1    = (const float*)d_in[9];
  const float* ry1    = (const float*)d_in[10];
  const float* rz2    = (const float*)d_in[11];

  float* ws    = (float*)d_ws;
  float* xq    = ws + WS_XQ;
  float* x1    = ws + WS_X1;
  float* ps1   = ws + WS_PS1;
  float* ps2   = ws + WS_PS2;
  float* bn_a  = ws + WS_BNA;
  float* bn_c  = ws + WS_BNC;
  float* gates = ws + WS_GATES;
  float* out   = (float*)d_out;

  hipLaunchKernelGGL(k_xq,  dim3(1024), dim3(320), 0, stream, x, qlin_w, qlin_b, xq, ps1, ps2);
  hipLaunchKernelGGL(k_bn,  dim3(41),   dim3(256), 0, stream, ps1, ps2, bn_g, bn_b,
                     rz1, ry1, rz2, bn_a, bn_c, gates);
  hipLaunchKernelGGL(k_qnn, dim3(2048), dim3(256), 0, stream, xq, bn_a, bn_c, gates, x1);
  hipLaunchKernelGGL(k_epi, dim3(1024), dim3(320), 0, stream, x, x1, clin_w, clin_b, lin_w, lin_b, out);
}